// Round 8
// baseline (86.221 us; speedup 1.0000x reference)
//
#include <hip/hip_runtime.h>
#include <stdint.h>

// ContrastiveLoss: mean over all pairs of (same-label ? d2 : relu(1-dist)^2)
// z: [8192,128] fp32, labels: [8192] int32. Output: 1 fp32 scalar.
//
// R17: A-RESIDENT blocks. Cold-premium ledger (all falsified): traffic
// (R13), warmup burst + nt (R14), barrier removal (R15 WORSE -10us),
// device-scope write-through (R16). Surviving model: depth-1 pipeline
// exposes per-step DMA completion (34KB + latency) at every vmcnt(0)+
// barrier; compute (~400cyc) << DMA (~1500-2500cyc cold) -> stall/step.
// Restructure: block = (row bi, chunk of <=4 consecutive bj). 544 blocks
// (sum ceil((64-r)/4)). A panel (16KB) + sqA/laA staged ONCE; only B
// (16KB+1KB) streams per step, double-buffered:
//   - per-step staged bytes 34->17KB (halves each exposed wait)
//   - total staged 71->43MB
//   - LDS 70->51KB -> 3 blocks/CU (launch_bounds(512,6)), +50% waves
// Compute core/epilogue byte-identical (LDS offsets unchanged; sqlab
// pointers split A-fixed/B-dbuf). prep = plain stores (R16 scope null).

#define NROWS 8192
#define DIMK  128
#define NB    64                     // 8192 / 128
#define NBLK  544                    // sum_{r<64} ceil((64-r)/4)

typedef __attribute__((ext_vector_type(4))) float f32x4;

#define AS_GLOBAL __attribute__((address_space(1)))
#define AS_LDS    __attribute__((address_space(3)))

// Convert z -> fp8 e4m3 with granule-swizzled rows: logical k lives in
// granule g = ((k>>3)&3)<<2 | (k>>5), stored at byte ((g^(row&15))<<3)+(k&7).
// Dot-invariant. Also per-row sum of squares of ROUNDED values (diag d2==0).
__global__ __launch_bounds__(256) void prep_kernel(
    const float* __restrict__ z, unsigned char* __restrict__ zb,
    float* __restrict__ sq) {
  int tid = threadIdx.x;
  int row = (blockIdx.x << 3) + (tid >> 5);          // 8 rows per block
  int c32 = tid & 31;                                // 32 lanes per row
  float4 x = ((const float4*)(z + (size_t)row * DIMK))[c32];
  int u = __builtin_amdgcn_cvt_pk_fp8_f32(x.x, x.y, 0, false);
  u     = __builtin_amdgcn_cvt_pk_fp8_f32(x.z, x.w, u, true);
  float r0 = __builtin_amdgcn_cvt_f32_fp8(u, 0);
  float r1 = __builtin_amdgcn_cvt_f32_fp8(u, 1);
  float r2 = __builtin_amdgcn_cvt_f32_fp8(u, 2);
  float r3 = __builtin_amdgcn_cvt_f32_fp8(u, 3);
  float s = (r0 * r0 + r1 * r1) + (r2 * r2 + r3 * r3);
  int k0 = c32 << 2;                                 // logical k of byte 0
  int g  = (((k0 >> 3) & 3) << 2) | (k0 >> 5);       // granule index
  int p  = ((g ^ (row & 15)) << 3) + (k0 & 7);       // 4B-aligned
  *(uint32_t*)(zb + (size_t)row * DIMK + p) = (uint32_t)u;
  #pragma unroll
  for (int off = 16; off; off >>= 1) s += __shfl_down(s, off, 32);
  if (c32 == 0) sq[row] = s;
}

// 544 blocks x 512 thr (8 waves, 4x2), 3 blocks/CU (51KB LDS).
// Block b -> row bi, chunk of up to 4 consecutive bj in [bi, 64).
// A panel resident; B panels double-buffered, 17KB per step.
__global__ __launch_bounds__(512, 6) void loss_kernel(
    const unsigned char* __restrict__ zb, const float* __restrict__ sq,
    const int* __restrict__ labels, float* __restrict__ out) {
  __shared__ __align__(16) unsigned char Abuf[16384];
  __shared__ __align__(16) unsigned char Bbuf[2][16384];
  __shared__ __align__(16) unsigned char sqlabA[1024];    // [sqA 512|laA 512]
  __shared__ __align__(16) unsigned char sqlabB[2][1024]; // [sqB 512|laB 512]
  __shared__ float red[8];

  int tid = threadIdx.x, lane = tid & 63, wave = tid >> 6;
  int wm = wave >> 1, wn = wave & 1;
  int lc = lane & 15;                                // frag row (A)/col (out)
  int q  = lane >> 4;                                // quad: k-granule select

  // ---- decode block -> (bi, bj0, nBt); uniform SALU loop ----
  int b = blockIdx.x;
  int bi = 0, base = 0;
  for (;;) {
    int c = (67 - bi) >> 2;                          // ceil((64-bi)/4)
    if (b < base + c) break;
    base += c; ++bi;
  }
  int chunk = b - base;
  int bj0 = bi + (chunk << 2);
  int nBt = (NB - bj0 < 4) ? (NB - bj0) : 4;         // 1..4 B tiles

  float psum_acc = 0.f;

  // ---- prologue: stage A panel + sqlabA + B0 + sqlabB0 ----
  {
    const unsigned char* Ab = zb + ((size_t)bi << 14);   // bi*128 rows *128B
    #pragma unroll
    for (int it = 0; it < 2; ++it) {
      int L0 = (it << 9) + (wave << 6);
      __builtin_amdgcn_global_load_lds(
          (const AS_GLOBAL void*)(uintptr_t)(Ab + (size_t)(L0 + lane) * 16),
          (AS_LDS void*)(uintptr_t)(&Abuf[(size_t)L0 * 16]), 16, 0, 0);
    }
    if (wave < 4 && lane < 16) {                      // sqA/laA, 256B each
      const char* p0 = (wave >= 2) ? (const char*)labels : (const char*)sq;
      const char* src = p0 + ((size_t)bi << 9) + ((wave & 1) << 8);
      __builtin_amdgcn_global_load_lds(
          (const AS_GLOBAL void*)(uintptr_t)(src + lane * 16),
          (AS_LDS void*)(uintptr_t)(&sqlabA[wave << 8]), 16, 0, 0);
    }
    // B0
    const unsigned char* Bb = zb + ((size_t)bj0 << 14);
    #pragma unroll
    for (int it = 0; it < 2; ++it) {
      int L0 = (it << 9) + (wave << 6);
      __builtin_amdgcn_global_load_lds(
          (const AS_GLOBAL void*)(uintptr_t)(Bb + (size_t)(L0 + lane) * 16),
          (AS_LDS void*)(uintptr_t)(&Bbuf[0][(size_t)L0 * 16]), 16, 0, 0);
    }
    if (wave >= 4 && lane < 16) {                     // sqB/laB, 256B each
      const char* p0 = (wave >= 6) ? (const char*)labels : (const char*)sq;
      const char* src = p0 + ((size_t)bj0 << 9) + ((wave & 1) << 8);
      __builtin_amdgcn_global_load_lds(
          (const AS_GLOBAL void*)(uintptr_t)(src + lane * 16),
          (AS_LDS void*)(uintptr_t)(&sqlabB[0][(wave - 4) << 8]), 16, 0, 0);
    }
  }

  const float* sqAl = (const float*)&sqlabA[0];
  const int*   laAl = (const int*)&sqlabA[512];

  int cur = 0;
  for (int ib = 0;; ++ib) {
    // ---- wait for current B tile's DMA (and A on first iter) ----
    asm volatile("s_waitcnt vmcnt(0)" ::: "memory");
    __syncthreads();   // implicit drain is free: vmcnt already 0

    bool hasNext = (ib + 1) < nBt;

    // ---- prefetch next B tile into the other buffer ----
    if (hasNext) {
      int bjn = bj0 + ib + 1;
      int nc = cur ^ 1;
      const unsigned char* Bb = zb + ((size_t)bjn << 14);
      #pragma unroll
      for (int it = 0; it < 2; ++it) {
        int L0 = (it << 9) + (wave << 6);
        __builtin_amdgcn_global_load_lds(
            (const AS_GLOBAL void*)(uintptr_t)(Bb + (size_t)(L0 + lane) * 16),
            (AS_LDS void*)(uintptr_t)(&Bbuf[nc][(size_t)L0 * 16]), 16, 0, 0);
      }
      if (wave >= 4 && lane < 16) {
        const char* p0 = (wave >= 6) ? (const char*)labels : (const char*)sq;
        const char* src = p0 + ((size_t)bjn << 9) + ((wave & 1) << 8);
        __builtin_amdgcn_global_load_lds(
            (const AS_GLOBAL void*)(uintptr_t)(src + lane * 16),
            (AS_LDS void*)(uintptr_t)(&sqlabB[nc][(wave - 4) << 8]), 16, 0, 0);
      }
    }

    // ---- compute tile (bi, bj0+ib) from Abuf / Bbuf[cur] ----
    const unsigned char* ldsA = &Abuf[0];
    const unsigned char* ldsB = &Bbuf[cur][0];
    const float* sqBl = (const float*)&sqlabB[cur][0];
    const int*   laBl = (const int*)&sqlabB[cur][512];

    f32x4 acc[2][4] = {};
    #pragma unroll
    for (int ks = 0; ks < 4; ++ks) {
      int so = ((((q << 2) | ks) ^ lc) << 3);        // swizzled slot offset
      long a0 = *(const long*)(ldsA + ((wm << 5)      + lc) * 128 + so);
      long a1 = *(const long*)(ldsA + ((wm << 5) + 16 + lc) * 128 + so);
      long b0 = *(const long*)(ldsB + ((wn << 6)      + lc) * 128 + so);
      long b1 = *(const long*)(ldsB + ((wn << 6) + 16 + lc) * 128 + so);
      long b2 = *(const long*)(ldsB + ((wn << 6) + 32 + lc) * 128 + so);
      long b3 = *(const long*)(ldsB + ((wn << 6) + 48 + lc) * 128 + so);
      acc[0][0] = __builtin_amdgcn_mfma_f32_16x16x32_fp8_fp8(a0, b0, acc[0][0], 0, 0, 0);
      acc[0][1] = __builtin_amdgcn_mfma_f32_16x16x32_fp8_fp8(a0, b1, acc[0][1], 0, 0, 0);
      acc[0][2] = __builtin_amdgcn_mfma_f32_16x16x32_fp8_fp8(a0, b2, acc[0][2], 0, 0, 0);
      acc[0][3] = __builtin_amdgcn_mfma_f32_16x16x32_fp8_fp8(a0, b3, acc[0][3], 0, 0, 0);
      acc[1][0] = __builtin_amdgcn_mfma_f32_16x16x32_fp8_fp8(a1, b0, acc[1][0], 0, 0, 0);
      acc[1][1] = __builtin_amdgcn_mfma_f32_16x16x32_fp8_fp8(a1, b1, acc[1][1], 0, 0, 0);
      acc[1][2] = __builtin_amdgcn_mfma_f32_16x16x32_fp8_fp8(a1, b2, acc[1][2], 0, 0, 0);
      acc[1][3] = __builtin_amdgcn_mfma_f32_16x16x32_fp8_fp8(a1, b3, acc[1][3], 0, 0, 0);
    }

    // ---- epilogue: branchless fast pass + ONE deferred vote ----
    // C/D layout: col = lane&15, row = (lane>>4)*4 + reg. If every d2 in
    // this wave's outputs >= 1: non-eq term EXACTLY 0, eq term exactly d2.
    int r0 = q << 2;
    float sn_[4]; int ln_[4];
    #pragma unroll
    for (int j = 0; j < 4; ++j) {
      int nidx = (wn << 6) + (j << 4) + lc;
      sn_[j] = sqBl[nidx]; ln_[j] = laBl[nidx];
    }
    float ps0 = 0.f, ps1 = 0.f, ps2 = 0.f, ps3 = 0.f;
    float mnall = 1e30f;
    #pragma unroll
    for (int i = 0; i < 2; ++i) {
      int mb = (wm << 5) + (i << 4) + r0;
      f32x4 sm4 = *(const f32x4*)&sqAl[mb];
      int4  lm4 = *(const int4*)&laAl[mb];
      #pragma unroll
      for (int j = 0; j < 4; ++j) {
        float d0  = fmaf(-2.f, acc[i][j][0], sm4[0] + sn_[j]);
        float d1  = fmaf(-2.f, acc[i][j][1], sm4[1] + sn_[j]);
        float d2_ = fmaf(-2.f, acc[i][j][2], sm4[2] + sn_[j]);
        float d3  = fmaf(-2.f, acc[i][j][3], sm4[3] + sn_[j]);
        mnall = fminf(mnall, fminf(fminf(d0, d1), fminf(d2_, d3)));
        ps0 += (lm4.x == ln_[j]) ? d0  : 0.f;
        ps1 += (lm4.y == ln_[j]) ? d1  : 0.f;
        ps2 += (lm4.z == ln_[j]) ? d2_ : 0.f;
        ps3 += (lm4.w == ln_[j]) ? d3  : 0.f;
      }
    }
    if (__builtin_expect(__any(mnall < 1.f), 0)) {
      // exact slow path (diagonal-touching waves only); acc still live
      ps0 = ps1 = ps2 = ps3 = 0.f;
      #pragma unroll
      for (int i = 0; i < 2; ++i) {
        int mb = (wm << 5) + (i << 4) + r0;
        f32x4 sm4 = *(const f32x4*)&sqAl[mb];
        int4  lm4 = *(const int4*)&laAl[mb];
        #pragma unroll
        for (int j = 0; j < 4; ++j) {
          float dc, tt;
          dc = fmaxf(fmaf(-2.f, acc[i][j][0], sm4[0] + sn_[j]), 0.f);
          tt = fmaxf(1.f - sqrtf(dc), 0.f);
          ps0 += (lm4.x == ln_[j]) ? dc : tt * tt;
          dc = fmaxf(fmaf(-2.f, acc[i][j][1], sm4[1] + sn_[j]), 0.f);
          tt = fmaxf(1.f - sqrtf(dc), 0.f);
          ps1 += (lm4.y == ln_[j]) ? dc : tt * tt;
          dc = fmaxf(fmaf(-2.f, acc[i][j][2], sm4[2] + sn_[j]), 0.f);
          tt = fmaxf(1.f - sqrtf(dc), 0.f);
          ps2 += (lm4.z == ln_[j]) ? dc : tt * tt;
          dc = fmaxf(fmaf(-2.f, acc[i][j][3], sm4[3] + sn_[j]), 0.f);
          tt = fmaxf(1.f - sqrtf(dc), 0.f);
          ps3 += (lm4.w == ln_[j]) ? dc : tt * tt;
        }
      }
    }
    float w = (bi == (bj0 + ib)) ? 1.f : 2.f;        // symmetry weight
    psum_acc += w * ((ps0 + ps1) + (ps2 + ps3));

    if (!hasNext) break;
    cur ^= 1;
  }

  // ---- block reduction + ONE device-scope atomicAdd ----
  psum_acc *= (1.f / (8192.f * 8192.f));             // 2^-26, exact
  #pragma unroll
  for (int off = 32; off; off >>= 1) psum_acc += __shfl_down(psum_acc, off);
  if (lane == 0) red[wave] = psum_acc;
  __syncthreads();
  if (tid == 0) {
    float sum = 0.f;
    #pragma unroll
    for (int k = 0; k < 8; ++k) sum += red[k];
    atomicAdd(out, sum);                             // device-scope default
  }
}

extern "C" void kernel_launch(void* const* d_in, const int* in_sizes, int n_in,
                              void* d_out, int out_size, void* d_ws, size_t ws_size,
                              hipStream_t stream) {
  const float* z      = (const float*)d_in[0];
  const int*   labels = (const int*)d_in[1];
  float*       out    = (float*)d_out;
  unsigned char* zb   = (unsigned char*)d_ws;                         // 1 MB
  float* sq           = (float*)((char*)d_ws + (size_t)NROWS * DIMK); // 32 KB

  prep_kernel<<<NROWS / 8, 256, 0, stream>>>(z, zb, sq);
  loss_kernel<<<NBLK, 512, 0, stream>>>(zb, sq, labels, out);
}

// Round 9
// 73.975 us; speedup vs baseline: 1.1655x; 1.1655x over previous
//
#include <hip/hip_runtime.h>
#include <stdint.h>

// ContrastiveLoss: mean over all pairs of (same-label ? d2 : relu(1-dist)^2)
// z: [8192,128] fp32, labels: [8192] int32. Output: 1 fp32 scalar.
//
// R18: R13 structure (best verified, 72.9us) with sq/labels staging REMOVED
// from the staging convoy: epilogue reads sq/labels directly from global
// (64KB, L2-hot; addressing verified in R15, absmax 0). Removes the masked
// lane<16 DMA from the vmcnt(0)+barrier critical path, drops LDS to 64KB.
// Structure ledger: R15 (no barriers) -10us; R17 (3/CU, short chains) -13us
// => depth of per-block dbuf chain is what matters, not TLP. R13 mapping
// (XCD-local rows, 512 blocks x ~4-5 steps, 2/CU) is the family optimum.
// prep plain stores (R16 device-scope null).

#define NROWS 8192
#define DIMK  128
#define NB    64                     // 8192 / 128
#define NPERS 512                    // persistent blocks (2 per CU)

typedef __attribute__((ext_vector_type(4))) float f32x4;

#define AS_GLOBAL __attribute__((address_space(1)))
#define AS_LDS    __attribute__((address_space(3)))

// Convert z -> fp8 e4m3 with granule-swizzled rows: logical k lives in
// granule g = ((k>>3)&3)<<2 | (k>>5), stored at byte ((g^(row&15))<<3)+(k&7).
// Dot-invariant. Also per-row sum of squares of ROUNDED values (diag d2==0).
__global__ __launch_bounds__(256) void prep_kernel(
    const float* __restrict__ z, unsigned char* __restrict__ zb,
    float* __restrict__ sq) {
  int tid = threadIdx.x;
  int row = (blockIdx.x << 3) + (tid >> 5);          // 8 rows per block
  int c32 = tid & 31;                                // 32 lanes per row
  float4 x = ((const float4*)(z + (size_t)row * DIMK))[c32];
  int u = __builtin_amdgcn_cvt_pk_fp8_f32(x.x, x.y, 0, false);
  u     = __builtin_amdgcn_cvt_pk_fp8_f32(x.z, x.w, u, true);
  float r0 = __builtin_amdgcn_cvt_f32_fp8(u, 0);
  float r1 = __builtin_amdgcn_cvt_f32_fp8(u, 1);
  float r2 = __builtin_amdgcn_cvt_f32_fp8(u, 2);
  float r3 = __builtin_amdgcn_cvt_f32_fp8(u, 3);
  float s = (r0 * r0 + r1 * r1) + (r2 * r2 + r3 * r3);
  int k0 = c32 << 2;                                 // logical k of byte 0
  int g  = (((k0 >> 3) & 3) << 2) | (k0 >> 5);       // granule index
  int p  = ((g ^ (row & 15)) << 3) + (k0 & 7);       // 4B-aligned
  *(uint32_t*)(zb + (size_t)row * DIMK + p) = (uint32_t)u;
  #pragma unroll
  for (int off = 16; off; off >>= 1) s += __shfl_down(s, off, 32);
  if (c32 == 0) sq[row] = s;
}

// XCD-local decode: XCD x owns rows r = x, x+8, ..., x+56. Row r has
// (NB - r) tiles. Flattened index n within the owned set -> (bi, bj).
// Integer-only, uniform (blockIdx-derived) -> compiles to SALU.
__device__ __forceinline__ void decode_tile_x(int x, int n, int& bi, int& bj) {
  int rem = n, k = 0, len = NB - x;       // L_k = NB - x - 8k
  while (rem >= len) { rem -= len; ++k; len -= 8; }
  bi = x + (k << 3);
  bj = bi + rem;
}

// Persistent: 512 blocks x 512 thr (8 waves, 4x2). Block b = (x = b&7,
// slot s = b>>3) computes its XCD's tiles n = s, s+64, ... (< 288-8x),
// double-buffered A/B staging (panels only). sq/labels read direct from
// global in the epilogue. Ends with ONE device-scope atomicAdd.
__global__ __launch_bounds__(512, 4) void loss_kernel(
    const unsigned char* __restrict__ zb, const float* __restrict__ sq,
    const int* __restrict__ labels, float* __restrict__ out) {
  __shared__ __align__(16) unsigned char buf[2][32768];   // [A 16K | B 16K]
  __shared__ float red[8];

  int tid = threadIdx.x, lane = tid & 63, wave = tid >> 6;
  int wm = wave >> 1, wn = wave & 1;
  int lc = lane & 15;                                // frag row (A)/col (out)
  int q  = lane >> 4;                                // quad: k-granule select

  float psum_acc = 0.f;

  int x = blockIdx.x & 7;                            // XCD (round-robin)
  int s = blockIdx.x >> 3;                           // slot within XCD
  int tcount = 288 - 8 * x;                          // tiles owned by XCD x
  int n = s;

  int bi, bj;
  decode_tile_x(x, n, bi, bj);

  // ---- prologue: stage tile n into buffer 0 ----
  {
    const unsigned char* Ab = zb + (((size_t)bi << 7) * DIMK);
    const unsigned char* Bb = zb + (((size_t)bj << 7) * DIMK);
    #pragma unroll
    for (int it = 0; it < 2; ++it) {
      int L0 = (it << 9) + (wave << 6);
      __builtin_amdgcn_global_load_lds(
          (const AS_GLOBAL void*)(uintptr_t)(Ab + (size_t)(L0 + lane) * 16),
          (AS_LDS void*)(uintptr_t)(&buf[0][(size_t)L0 * 16]), 16, 0, 0);
      __builtin_amdgcn_global_load_lds(
          (const AS_GLOBAL void*)(uintptr_t)(Bb + (size_t)(L0 + lane) * 16),
          (AS_LDS void*)(uintptr_t)(&buf[0][16384 + (size_t)L0 * 16]), 16, 0, 0);
    }
  }

  int cur = 0;
  for (;; n += 64) {
    int nn = n + 64;
    bool hasNext = nn < tcount;

    // ---- wait for current tile's DMA (issued a full iteration ago) ----
    asm volatile("s_waitcnt vmcnt(0)" ::: "memory");
    __syncthreads();   // implicit drain is free: vmcnt already 0

    // ---- prefetch next tile into the other buffer ----
    int bin = bi, bjn = bj;
    if (hasNext) {
      decode_tile_x(x, nn, bin, bjn);
      int nc = cur ^ 1;
      const unsigned char* Ab = zb + (((size_t)bin << 7) * DIMK);
      const unsigned char* Bb = zb + (((size_t)bjn << 7) * DIMK);
      #pragma unroll
      for (int it = 0; it < 2; ++it) {
        int L0 = (it << 9) + (wave << 6);
        __builtin_amdgcn_global_load_lds(
            (const AS_GLOBAL void*)(uintptr_t)(Ab + (size_t)(L0 + lane) * 16),
            (AS_LDS void*)(uintptr_t)(&buf[nc][(size_t)L0 * 16]), 16, 0, 0);
        __builtin_amdgcn_global_load_lds(
            (const AS_GLOBAL void*)(uintptr_t)(Bb + (size_t)(L0 + lane) * 16),
            (AS_LDS void*)(uintptr_t)(&buf[nc][16384 + (size_t)L0 * 16]), 16, 0, 0);
      }
    }

    // ---- compute tile n from buf[cur] ----
    const unsigned char* ldsA = &buf[cur][0];
    const unsigned char* ldsB = &buf[cur][16384];

    f32x4 acc[2][4] = {};
    #pragma unroll
    for (int ks = 0; ks < 4; ++ks) {
      int so = ((((q << 2) | ks) ^ lc) << 3);        // swizzled slot offset
      long a0 = *(const long*)(ldsA + ((wm << 5)      + lc) * 128 + so);
      long a1 = *(const long*)(ldsA + ((wm << 5) + 16 + lc) * 128 + so);
      long b0 = *(const long*)(ldsB + ((wn << 6)      + lc) * 128 + so);
      long b1 = *(const long*)(ldsB + ((wn << 6) + 16 + lc) * 128 + so);
      long b2 = *(const long*)(ldsB + ((wn << 6) + 32 + lc) * 128 + so);
      long b3 = *(const long*)(ldsB + ((wn << 6) + 48 + lc) * 128 + so);
      acc[0][0] = __builtin_amdgcn_mfma_f32_16x16x32_fp8_fp8(a0, b0, acc[0][0], 0, 0, 0);
      acc[0][1] = __builtin_amdgcn_mfma_f32_16x16x32_fp8_fp8(a0, b1, acc[0][1], 0, 0, 0);
      acc[0][2] = __builtin_amdgcn_mfma_f32_16x16x32_fp8_fp8(a0, b2, acc[0][2], 0, 0, 0);
      acc[0][3] = __builtin_amdgcn_mfma_f32_16x16x32_fp8_fp8(a0, b3, acc[0][3], 0, 0, 0);
      acc[1][0] = __builtin_amdgcn_mfma_f32_16x16x32_fp8_fp8(a1, b0, acc[1][0], 0, 0, 0);
      acc[1][1] = __builtin_amdgcn_mfma_f32_16x16x32_fp8_fp8(a1, b1, acc[1][1], 0, 0, 0);
      acc[1][2] = __builtin_amdgcn_mfma_f32_16x16x32_fp8_fp8(a1, b2, acc[1][2], 0, 0, 0);
      acc[1][3] = __builtin_amdgcn_mfma_f32_16x16x32_fp8_fp8(a1, b3, acc[1][3], 0, 0, 0);
    }

    // ---- epilogue: branchless fast pass + ONE deferred vote ----
    // sq/labels read DIRECTLY from global (L2-hot, wave-private, overlaps
    // MFMA; verified addressing = R15). C/D layout: col = lane&15,
    // row = (lane>>4)*4 + reg. If every d2 in this wave's outputs >= 1:
    // non-eq term EXACTLY 0, eq term exactly d2.
    const float* sqA = sq     + ((size_t)bi << 7);
    const int*   laA = labels + ((size_t)bi << 7);
    const float* sqB = sq     + ((size_t)bj << 7);
    const int*   laB = labels + ((size_t)bj << 7);

    int r0 = q << 2;
    float sn_[4]; int ln_[4];
    #pragma unroll
    for (int j = 0; j < 4; ++j) {
      int nidx = (wn << 6) + (j << 4) + lc;
      sn_[j] = sqB[nidx]; ln_[j] = laB[nidx];
    }
    float ps0 = 0.f, ps1 = 0.f, ps2 = 0.f, ps3 = 0.f;
    float mnall = 1e30f;
    #pragma unroll
    for (int i = 0; i < 2; ++i) {
      int mb = (wm << 5) + (i << 4) + r0;
      f32x4 sm4 = *(const f32x4*)&sqA[mb];
      int4  lm4 = *(const int4*)&laA[mb];
      #pragma unroll
      for (int j = 0; j < 4; ++j) {
        float d0  = fmaf(-2.f, acc[i][j][0], sm4[0] + sn_[j]);
        float d1  = fmaf(-2.f, acc[i][j][1], sm4[1] + sn_[j]);
        float d2_ = fmaf(-2.f, acc[i][j][2], sm4[2] + sn_[j]);
        float d3  = fmaf(-2.f, acc[i][j][3], sm4[3] + sn_[j]);
        mnall = fminf(mnall, fminf(fminf(d0, d1), fminf(d2_, d3)));
        ps0 += (lm4.x == ln_[j]) ? d0  : 0.f;
        ps1 += (lm4.y == ln_[j]) ? d1  : 0.f;
        ps2 += (lm4.z == ln_[j]) ? d2_ : 0.f;
        ps3 += (lm4.w == ln_[j]) ? d3  : 0.f;
      }
    }
    if (__builtin_expect(__any(mnall < 1.f), 0)) {
      // exact slow path (diagonal-touching waves only); acc still live
      ps0 = ps1 = ps2 = ps3 = 0.f;
      #pragma unroll
      for (int i = 0; i < 2; ++i) {
        int mb = (wm << 5) + (i << 4) + r0;
        f32x4 sm4 = *(const f32x4*)&sqA[mb];
        int4  lm4 = *(const int4*)&laA[mb];
        #pragma unroll
        for (int j = 0; j < 4; ++j) {
          float dc, tt;
          dc = fmaxf(fmaf(-2.f, acc[i][j][0], sm4[0] + sn_[j]), 0.f);
          tt = fmaxf(1.f - sqrtf(dc), 0.f);
          ps0 += (lm4.x == ln_[j]) ? dc : tt * tt;
          dc = fmaxf(fmaf(-2.f, acc[i][j][1], sm4[1] + sn_[j]), 0.f);
          tt = fmaxf(1.f - sqrtf(dc), 0.f);
          ps1 += (lm4.y == ln_[j]) ? dc : tt * tt;
          dc = fmaxf(fmaf(-2.f, acc[i][j][2], sm4[2] + sn_[j]), 0.f);
          tt = fmaxf(1.f - sqrtf(dc), 0.f);
          ps2 += (lm4.z == ln_[j]) ? dc : tt * tt;
          dc = fmaxf(fmaf(-2.f, acc[i][j][3], sm4[3] + sn_[j]), 0.f);
          tt = fmaxf(1.f - sqrtf(dc), 0.f);
          ps3 += (lm4.w == ln_[j]) ? dc : tt * tt;
        }
      }
    }
    float w = (bi == bj) ? 1.f : 2.f;                // symmetry weight
    psum_acc += w * ((ps0 + ps1) + (ps2 + ps3));

    if (!hasNext) break;
    bi = bin; bj = bjn; cur ^= 1;
  }

  // ---- block reduction + ONE device-scope atomicAdd ----
  psum_acc *= (1.f / (8192.f * 8192.f));             // 2^-26, exact
  #pragma unroll
  for (int off = 32; off; off >>= 1) psum_acc += __shfl_down(psum_acc, off);
  if (lane == 0) red[wave] = psum_acc;
  __syncthreads();
  if (tid == 0) {
    float sum = 0.f;
    #pragma unroll
    for (int k = 0; k < 8; ++k) sum += red[k];
    atomicAdd(out, sum);                             // device-scope default
  }
}

extern "C" void kernel_launch(void* const* d_in, const int* in_sizes, int n_in,
                              void* d_out, int out_size, void* d_ws, size_t ws_size,
                              hipStream_t stream) {
  const float* z      = (const float*)d_in[0];
  const int*   labels = (const int*)d_in[1];
  float*       out    = (float*)d_out;
  unsigned char* zb   = (unsigned char*)d_ws;                         // 1 MB
  float* sq           = (float*)((char*)d_ws + (size_t)NROWS * DIMK); // 32 KB

  prep_kernel<<<NROWS / 8, 256, 0, stream>>>(z, zb, sq);
  loss_kernel<<<NPERS, 512, 0, stream>>>(zb, sq, labels, out);
}